// Round 15
// baseline (604.594 us; speedup 1.0000x reference)
//
#include <hip/hip_runtime.h>
#include <float.h>
#include <math.h>

#define VOCAB 128000
#define DIM   2048
#define SEQL  8
#define NB    32
#define SCAP  4096   // LDS candidate slots per row (expected ~100-250 used)
#define QD    512    // D-quarter

// ---------- helpers ----------
__device__ __forceinline__ unsigned f2sortable(float x){
  unsigned u = __float_as_uint(x);
  return (u & 0x80000000u) ? ~u : (u | 0x80000000u);  // monotone: bigger float -> bigger uint
}
__device__ __forceinline__ unsigned rotl32(unsigned x, int d){
  return (x << d) | (x >> (32 - d));
}

// JAX threefry gumbel, PARTITIONABLE path (verified passing r6/r8-r14): counter-mode,
// cipher input (0, n), key (0,42), output = XOR fold of the two output words.
__device__ float jax_gumbel(unsigned n){
  unsigned x0 = 0u, x1 = n;
  const unsigned k0 = 0u, k1 = 42u;
  const unsigned k2 = 0x1BD11BDAu ^ k0 ^ k1;
  x0 += k0; x1 += k1;
#define TFR(r) { x0 += x1; x1 = rotl32(x1, r); x1 ^= x0; }
  TFR(13) TFR(15) TFR(26) TFR(6)
  x0 += k1; x1 += k2 + 1u;
  TFR(17) TFR(29) TFR(16) TFR(24)
  x0 += k2; x1 += k0 + 2u;
  TFR(13) TFR(15) TFR(26) TFR(6)
  x0 += k0; x1 += k1 + 3u;
  TFR(17) TFR(29) TFR(16) TFR(24)
  x0 += k1; x1 += k2 + 4u;
  TFR(13) TFR(15) TFR(26) TFR(6)
  x0 += k2; x1 += k0 + 5u;
#undef TFR
  unsigned bits = x0 ^ x1;
  float f = __uint_as_float((bits >> 9) | 0x3f800000u) - 1.0f; // [0,1)
  float u = f + 1.17549435e-38f;
  return -logf(-logf(u));
}

// ---------- K1 (split-D): partial = hs[:, qD] . E[:, qD]^T, accumulated into C ----------
// Stage-once design: hs quarter (32 b x 512 d = 64 KB) staged to LDS ONCE, one barrier,
// then a BARRIER-FREE slice loop -> E loads pipeline freely (no vmcnt(0) drains).
// 4 sequential launches q=0..3: q0 writes, q1-2 add, q3 adds + softcap + temp.
__global__ __launch_bounds__(256) void k_logits_part(
    const float* __restrict__ E, const float* __restrict__ HS,
    const float* __restrict__ temps, const int* __restrict__ posp,
    float* __restrict__ C, int q, int first, int last)
{
  __shared__ float hs_s[NB * QD];      // 64 KB
  __shared__ float tile[NB * NB];      // 4 KB transpose buffer
  const int tid  = threadIdx.x;
  const int w    = tid >> 6;
  const int lane = tid & 63;
  const int g    = lane >> 4;
  const int qi   = lane & 15;
  const int pos  = posp[0];
  const int vbase = blockIdx.x * 32;
  const int vw    = vbase + w * 8;
  const int qd0   = q * QD;

  // stage hs quarter: 4096 float4, 16 per thread, coalesced
#pragma unroll
  for (int k = 0; k < 16; ++k){
    const int ff = tid + k * 256;        // f4 index into hs_s
    const int b  = ff >> 7;              // /128 f4 per row
    const int d4 = ff & 127;
    float4 v = *(const float4*)(HS + ((size_t)(b * SEQL + pos)) * DIM + qd0 + d4 * 4);
    *(float4*)&hs_s[ff * 4] = v;
  }

  float acc[8][8];
#pragma unroll
  for (int j = 0; j < 8; ++j)
#pragma unroll
    for (int bl = 0; bl < 8; ++bl) acc[j][bl] = 0.f;

  __syncthreads();                       // hs quarter visible; ONLY barrier before epilogue

  const float* Eb = E + (size_t)vw * DIM + qd0 + qi * 4;

  for (int s = 0; s < 8; ++s){           // 8 slices x 64 d, NO barriers
    float4 e[8];
#pragma unroll
    for (int j = 0; j < 8; ++j)
      e[j] = *(const float4*)(Eb + (size_t)j * DIM + s * 64);
    const float* hb = &hs_s[0];
#pragma unroll
    for (int bl = 0; bl < 8; ++bl){
      float4 h = *(const float4*)(hb + (g * 8 + bl) * QD + s * 64 + qi * 4);
#pragma unroll
      for (int j = 0; j < 8; ++j){
        acc[j][bl] = fmaf(e[j].x, h.x, acc[j][bl]);
        acc[j][bl] = fmaf(e[j].y, h.y, acc[j][bl]);
        acc[j][bl] = fmaf(e[j].z, h.z, acc[j][bl]);
        acc[j][bl] = fmaf(e[j].w, h.w, acc[j][bl]);
      }
    }
  }

  // butterfly-reduce partials across the 16 qi-lanes of each b-quarter group
#pragma unroll
  for (int j = 0; j < 8; ++j)
#pragma unroll
    for (int bl = 0; bl < 8; ++bl){
      float v = acc[j][bl];
      v += __shfl_xor(v, 1, 64);
      v += __shfl_xor(v, 2, 64);
      v += __shfl_xor(v, 4, 64);
      v += __shfl_xor(v, 8, 64);
      acc[j][bl] = v;
    }
  if (qi == 0){
#pragma unroll
    for (int j = 0; j < 8; ++j)
#pragma unroll
      for (int bl = 0; bl < 8; ++bl)
        tile[(g * 8 + bl) * 32 + w * 8 + j] = acc[j][bl];
  }
  __syncthreads();
  { // epilogue: 32 b x 32 v = 256 float4; accumulate across launches
    const int b = tid >> 3, vq = tid & 7;
    float* cp = C + (size_t)b * VOCAB + vbase + vq * 4;
    float4 tv = *(const float4*)&tile[b * 32 + vq * 4];
    if (!first){
      float4 prev = *(const float4*)cp;
      tv.x += prev.x; tv.y += prev.y; tv.z += prev.z; tv.w += prev.w;
    }
    if (last){
      const float tmp = temps[b];
      tv.x = (tanhf(tv.x / 30.f) * 30.f) / tmp;
      tv.y = (tanhf(tv.y / 30.f) * 30.f) / tmp;
      tv.z = (tanhf(tv.z / 30.f) * 30.f) / tmp;
      tv.w = (tanhf(tv.w / 30.f) * 30.f) / tmp;
    }
    *(float4*)cp = tv;
  }
}

// ---------- K2 (fused): per-row stats + exact top-64 + top-k/top-p + gumbel sample ----------
// One block (1024 thr) per row. Zero global scratch. LDS = 4+4+16+16+16 = 56 KB.
__global__ __launch_bounds__(1024) void k_sample_fused(
    const float* __restrict__ C,
    const float* __restrict__ tps, const int* __restrict__ tks,
    float* __restrict__ out_tok)
{
  const int b = blockIdx.x, t = threadIdx.x;
  const float* row = C + (size_t)b * VOCAB;
  __shared__ float red[1024];
  __shared__ unsigned ps[1024];
  __shared__ unsigned hist[4096];     // 12-bit sortable prefix
  __shared__ float    cval_s[SCAP];
  __shared__ int      cidx_s[SCAP];
  __shared__ int tbin_s;
  __shared__ unsigned cnt_s;

  if (t == 0) cnt_s = 0u;

  // pass 1: row max (order-independent)
  float m = -FLT_MAX;
  for (int f = t; f < VOCAB / 4; f += 1024){
    float4 x = ((const float4*)row)[f];
    m = fmaxf(m, fmaxf(fmaxf(x.x, x.y), fmaxf(x.z, x.w)));
  }
  red[t] = m; __syncthreads();
  for (int sft = 512; sft > 0; sft >>= 1){
    if (t < sft) red[t] = fmaxf(red[t], red[t + sft]);
    __syncthreads();
  }
  m = red[0];
  for (int i = t; i < 4096; i += 1024) hist[i] = 0u;
  __syncthreads();

  // pass 2: sumexp + 12-bit histogram
  float zs = 0.f;
  for (int f = t; f < VOCAB / 4; f += 1024){
    float4 x4 = ((const float4*)row)[f];
    float xs[4] = {x4.x, x4.y, x4.z, x4.w};
#pragma unroll
    for (int c = 0; c < 4; ++c){
      zs += expf(xs[c] - m);
      atomicAdd(&hist[f2sortable(xs[c]) >> 20], 1u);
    }
  }
  red[t] = zs; __syncthreads();
  for (int sft = 512; sft > 0; sft >>= 1){
    if (t < sft) red[t] += red[t + sft];
    __syncthreads();
  }
  const float Z = red[0];

  // suffix scan over 1024 thread-partials (4 bins each) -> bin containing 64th-largest
  unsigned s_t = 0u;
#pragma unroll
  for (int k = 0; k < 4; ++k) s_t += hist[t * 4 + k];
  ps[t] = s_t; __syncthreads();
  for (int off = 1; off < 1024; off <<= 1){
    unsigned v = ps[t] + ((t + off < 1024) ? ps[t + off] : 0u);
    __syncthreads();
    ps[t] = v;
    __syncthreads();
  }
  const unsigned Sstrict = ps[t] - s_t;       // count in threads > t
  if (Sstrict < 64u && ps[t] >= 64u){
    unsigned c = Sstrict;
    for (int bb = 3; bb >= 0; --bb){
      c += hist[t * 4 + bb];
      if (c >= 64u){ tbin_s = t * 4 + bb; break; }
    }
  }
  __syncthreads();
  const unsigned thr = ((unsigned)tbin_s) << 20;

  // pass 3: collect candidates (exact superset of top-64 by construction)
  for (int f = t; f < VOCAB / 4; f += 1024){
    float4 x4 = ((const float4*)row)[f];
    float xs[4] = {x4.x, x4.y, x4.z, x4.w};
#pragma unroll
    for (int c = 0; c < 4; ++c){
      if (f2sortable(xs[c]) >= thr){
        unsigned slot = atomicAdd(&cnt_s, 1u);
        if (slot < (unsigned)SCAP){
          cval_s[slot] = xs[c];
          cidx_s[slot] = f * 4 + c;
        }
      }
    }
  }
  __syncthreads();
  int cn = (int)cnt_s; if (cn > SCAP) cn = SCAP;

  // transform candidates to reference probs in place
  for (int j = t; j < cn; j += 1024)
    cval_s[j] = expf(cval_s[j] - m) / Z;
  __syncthreads();

  // wave 0 only: exact 64-rank predicate-walk by (p desc, idx asc), then mask+sample
  if (t < 64){
    float my_sp = 0.f; int my_si = 0;
    float lp = FLT_MAX; int li = -1;
    for (int r = 0; r < 64; ++r){
      float bp = -1.f; int bi = 0x7fffffff;
      for (int j = t; j < cn; j += 64){
        float p = cval_s[j]; int id = cidx_s[j];
        bool valid = (p < lp) || (p == lp && id > li);
        if (valid && (p > bp || (p == bp && id < bi))){ bp = p; bi = id; }
      }
#pragma unroll
      for (int off = 32; off >= 1; off >>= 1){
        float op = __shfl_xor(bp, off, 64);
        int   oi = __shfl_xor(bi, off, 64);
        if (op > bp || (op == bp && oi < bi)){ bp = op; bi = oi; }
      }
      if (t == r){ my_sp = bp; my_si = bi; }
      lp = bp; li = bi;
    }

    const float tp = tps[b];
    const int   tk = tks[b];
    float c = 0.f, sren = 0.f;
    bool keep_me = false;
    for (int j = 0; j < 64; ++j){
      float pj = __shfl(my_sp, j, 64);
      c = c + pj;
      float excl = c - pj;                      // cum - probs_sort
      bool keep = (!(excl > tp)) && (j < tk);
      if (j == t) keep_me = keep;
      if (keep) sren = sren + pj;
    }

    float score = -FLT_MAX;
    int vid = my_si;
    if (keep_me){
      float pf = my_sp / sren;
      score = logf(pf) + jax_gumbel((unsigned)(b * VOCAB + vid));
    }
    float bs = score; int bv = vid;
#pragma unroll
    for (int off = 32; off >= 1; off >>= 1){
      float os = __shfl_xor(bs, off, 64);
      int   ov = __shfl_xor(bv, off, 64);
      if (os > bs || (os == bs && ov < bv)){ bs = os; bv = ov; }
    }
    if (t == 0) out_tok[b] = (float)bv;
  }
}

extern "C" void kernel_launch(void* const* d_in, const int* in_sizes, int n_in,
                              void* d_out, int out_size, void* d_ws, size_t ws_size,
                              hipStream_t stream)
{
  (void)in_sizes; (void)n_in; (void)out_size; (void)d_ws; (void)ws_size;
  const float* emb   = (const float*)d_in[0];
  const float* hs    = (const float*)d_in[1];
  const float* temps = (const float*)d_in[2];
  const float* tps   = (const float*)d_in[3];
  const int*   posp  = (const int*)d_in[4];
  const int*   tks   = (const int*)d_in[5];
  float* out = (float*)d_out;
  float* C   = out + NB;                    // logits [32][128000]; tokens in out[0..31]

  for (int q = 0; q < 4; ++q)
    k_logits_part<<<dim3(VOCAB / 32), dim3(256), 0, stream>>>(
        emb, hs, temps, posp, C, q, q == 0 ? 1 : 0, q == 3 ? 1 : 0);
  k_sample_fused<<<dim3(NB), dim3(1024), 0, stream>>>(C, tps, tks, out);
}